// Round 8
// baseline (592.202 us; speedup 1.0000x reference)
//
#include <hip/hip_runtime.h>
#include <math.h>

#define NB 8
#define IC 256
#define CC 64
#define HH 128
#define WW 128
#define NN (HH*WW)      // 16384
#define NKW 64          // k-chunks for gramW (8192/64 = 128 k per chunk)
#define NKC 64          // n-chunks for gramC (16384/64 = 256 n per chunk)

// ---------------- workspace layout (floats) ----------------
static constexpr size_t SZ_INP  = (size_t)NB * CC * NN;            // 8,388,608
static constexpr size_t OFF_INP = 0;
static constexpr size_t OFF_S   = OFF_INP + SZ_INP;                // s AND pW (aliased)
static constexpr size_t OFF_PC  = OFF_S + SZ_INP;                  // pC: NB*NKC*4096
static constexpr size_t OFF_TW  = OFF_PC + (size_t)NB * NKC * 4096;
static constexpr size_t OFF_TC  = OFF_TW + (size_t)NB * 16384;
static constexpr size_t OFF_WT  = OFF_TC + (size_t)NB * 4096;      // w_in_t [256 i][64 o]
static constexpr size_t OFF_WOT = OFF_WT + 16384;                  // w_out_t [64 c][256 o]

// ---------------- tiny transpose of both weight matrices ----------------
__global__ __launch_bounds__(256) void k_wt(
    const float* __restrict__ w_in, const float* __restrict__ w_out,
    float* __restrict__ w_in_t, float* __restrict__ w_out_t)
{
    const int idx = blockIdx.x * 256 + threadIdx.x;   // 0..32767
    if (idx < 16384) {
        const int o = idx & 63, i = idx >> 6;         // w_in_t[i][o] = w_in[o][i]
        w_in_t[idx] = w_in[o * IC + i];
    } else {
        const int j = idx - 16384;
        const int o = j & 255, c = j >> 8;            // w_out_t[c][o] = w_out[o][c]
        w_out_t[j] = w_out[o * CC + c];
    }
}

// ---------------- inconv: inp[b,o,n] = sum_i w_in[o,i]*x[b,i,n] + b_in[o] ----------------
// grid (NN/128, NB), block 128 (2 waves). 64o x 128n tile, 8x8/thread, NO LDS, NO barriers.
// Rationale: rounds 0-7 pinned every LDS-staged variant at ~80us, VALUBusy ~40% — the LDS
// round-trip (1 B/FMA) caps VALU duty at ~40%. Here both operands come straight from
// L1/L2: x-load has 16 distinct addrs/wave (4-way broadcast, 256B contiguous -> L1 dedups
// the 8-fold o-reuse, L2 sees ~compulsory 128KB/block); w-load has 4 distinct 16B
// addrs/wave (wt is 64KB, L2-resident). 4 VMEM per 64 VALU; compiler pipelines freely.
__global__ __launch_bounds__(128) void k_inconv(
    const float* __restrict__ x, const float* __restrict__ wt,
    const float* __restrict__ b_in, float* __restrict__ inp)
{
    const int b  = blockIdx.y;
    const int n0 = blockIdx.x * 128;
    const int t  = threadIdx.x;
    const int og = t >> 4;           // 0..7 : o = og*8..+8
    const int ng = t & 15;           // n cols: n0+ng*4 and n0+64+ng*4

    float acc[8][8];
#pragma unroll
    for (int p = 0; p < 8; p++)
#pragma unroll
        for (int q = 0; q < 8; q++) acc[p][q] = 0.f;

    const float* xp = x + (size_t)b * IC * NN + n0 + ng * 4;
    const float* wp = wt + og * 8;

#pragma unroll 4
    for (int i = 0; i < IC; ++i) {
        const float4 xa = *(const float4*)(xp);
        const float4 xb = *(const float4*)(xp + 64);
        const float4 wa = *(const float4*)(wp);
        const float4 wb = *(const float4*)(wp + 4);
        xp += NN;
        wp += 64;
        const float wv[8] = {wa.x, wa.y, wa.z, wa.w, wb.x, wb.y, wb.z, wb.w};
        const float xv[8] = {xa.x, xa.y, xa.z, xa.w, xb.x, xb.y, xb.z, xb.w};
#pragma unroll
        for (int p = 0; p < 8; p++)
#pragma unroll
            for (int q = 0; q < 8; q++) acc[p][q] += wv[p] * xv[q];
    }

#pragma unroll
    for (int p = 0; p < 8; ++p) {
        const int oo = og * 8 + p;
        const float bo = b_in[oo];
        float* base = inp + ((size_t)b * CC + oo) * NN + n0;
        *(float4*)(base + ng * 4) =
            make_float4(acc[p][0] + bo, acc[p][1] + bo, acc[p][2] + bo, acc[p][3] + bo);
        *(float4*)(base + 64 + ng * 4) =
            make_float4(acc[p][4] + bo, acc[p][5] + bo, acc[p][6] + bo, acc[p][7] + bo);
    }
}

// ---------------- gram W partials ----------------
__global__ __launch_bounds__(256) void k_gramW(const float* __restrict__ inp, float* __restrict__ pW)
{
    __shared__ float xs[8 * 128];
    const int b = blockIdx.y, kc = blockIdx.x;
    const int t = threadIdx.x, tx = t & 15, ty = t >> 4;
    const float* Xb = inp + (size_t)b * CC * NN;
    const int k0 = kc * ((CC * HH) / NKW);   // 128 k per chunk

    float acc[8][8];
#pragma unroll
    for (int i = 0; i < 8; i++)
#pragma unroll
        for (int j = 0; j < 8; j++) acc[i][j] = 0.f;

    for (int kk = k0; kk < k0 + (CC * HH) / NKW; kk += 8) {
        __syncthreads();
        for (int idx = t; idx < 1024; idx += 256)
            xs[idx] = Xb[((size_t)kk + (idx >> 7)) * WW + (idx & 127)];
        __syncthreads();
#pragma unroll
        for (int k = 0; k < 8; k++) {
            const float* row = xs + k * 128;
            float4 t0 = *(const float4*)(row + ty * 8);
            float4 t1 = *(const float4*)(row + ty * 8 + 4);
            float4 u0 = *(const float4*)(row + tx * 8);
            float4 u1 = *(const float4*)(row + tx * 8 + 4);
            float av[8] = {t0.x, t0.y, t0.z, t0.w, t1.x, t1.y, t1.z, t1.w};
            float bv[8] = {u0.x, u0.y, u0.z, u0.w, u1.x, u1.y, u1.z, u1.w};
#pragma unroll
            for (int i = 0; i < 8; i++)
#pragma unroll
                for (int j = 0; j < 8; j++) acc[i][j] += av[i] * bv[j];
        }
    }
    float* dst = pW + ((size_t)b * NKW + kc) * 16384;
#pragma unroll
    for (int i = 0; i < 8; i++)
#pragma unroll
        for (int j = 0; j < 8; j += 4) {
            float4 v = make_float4(acc[i][j], acc[i][j + 1], acc[i][j + 2], acc[i][j + 3]);
            *(float4*)(dst + (ty * 8 + i) * 128 + tx * 8 + j) = v;
        }
}

__global__ __launch_bounds__(256) void k_redW(const float* __restrict__ pW, float* __restrict__ Tw)
{
    const int b = blockIdx.y;
    const int idx = blockIdx.x * 256 + threadIdx.x;
    const float* p = pW + (size_t)b * NKW * 16384 + idx;
    float acc = 0.f;
#pragma unroll
    for (int k = 0; k < NKW; k++) acc += p[(size_t)k * 16384];
    Tw[(size_t)b * 16384 + idx] = acc;
}

// softmax over w (rows) per column v; grid (NB, 4), block 1024: 32 v-cols x 128 rows
__global__ __launch_bounds__(1024) void k_softW(float* __restrict__ Tw)
{
    __shared__ float red[32 * 33];
    const int b = blockIdx.x, v0 = blockIdx.y * 32;
    const int t = threadIdx.x;
    const int vc = t & 31, wg = t >> 5;      // 32 row-groups x 4 rows
    float* S = Tw + (size_t)b * 16384 + v0 + vc;

    float v[4];
    float m = -3.4e38f;
#pragma unroll
    for (int j = 0; j < 4; j++) { v[j] = S[(wg * 4 + j) * 128]; m = fmaxf(m, v[j]); }
    red[wg * 33 + vc] = m;
    __syncthreads();
    for (int st = 16; st > 0; st >>= 1) {
        if (wg < st) red[wg * 33 + vc] = fmaxf(red[wg * 33 + vc], red[(wg + st) * 33 + vc]);
        __syncthreads();
    }
    m = red[vc];
    __syncthreads();
    float sum = 0.f;
#pragma unroll
    for (int j = 0; j < 4; j++) { v[j] = __expf(v[j] - m); sum += v[j]; }
    red[wg * 33 + vc] = sum;
    __syncthreads();
    for (int st = 16; st > 0; st >>= 1) {
        if (wg < st) red[wg * 33 + vc] += red[(wg + st) * 33 + vc];
        __syncthreads();
    }
    const float inv = 1.f / red[vc];
#pragma unroll
    for (int j = 0; j < 4; j++) S[(wg * 4 + j) * 128] = v[j] * inv;
}

// ---------------- gram C partials: transposed LDS tile [n][c] ----------------
__global__ __launch_bounds__(256) void k_gramC(const float* __restrict__ inp, float* __restrict__ pC)
{
    __shared__ float xt[32 * 68];   // [n_local][c], stride 68
    const int b = blockIdx.y, nc = blockIdx.x;
    const int t = threadIdx.x, tx = t & 15, ty = t >> 4;
    const float* ip = inp + (size_t)b * CC * NN;
    const int n0 = nc * (NN / NKC);

    float acc[4][4];
#pragma unroll
    for (int i = 0; i < 4; i++)
#pragma unroll
        for (int j = 0; j < 4; j++) acc[i][j] = 0.f;

    const int scc = t >> 2;
    const int sn  = (t & 3) * 8;

    for (int nt = 0; nt < NN / NKC; nt += 32) {
        __syncthreads();
        {
            const float* src = ip + (size_t)scc * NN + n0 + nt + sn;
            float v[8];
            *(float4*)(v)     = *(const float4*)(src);
            *(float4*)(v + 4) = *(const float4*)(src + 4);
#pragma unroll
            for (int j = 0; j < 8; j++) xt[(sn + j) * 68 + scc] = v[j];
        }
        __syncthreads();
#pragma unroll 8
        for (int nn = 0; nn < 32; nn++) {
            const float4 a4 = *(const float4*)(xt + nn * 68 + ty * 4);
            const float4 e4 = *(const float4*)(xt + nn * 68 + tx * 4);
            const float av[4] = {a4.x, a4.y, a4.z, a4.w};
            const float ev[4] = {e4.x, e4.y, e4.z, e4.w};
#pragma unroll
            for (int i = 0; i < 4; i++)
#pragma unroll
                for (int j = 0; j < 4; j++) acc[i][j] += av[i] * ev[j];
        }
    }
    float* dst = pC + ((size_t)b * NKC + nc) * 4096;
#pragma unroll
    for (int i = 0; i < 4; i++) {
        float4 v = make_float4(acc[i][0], acc[i][1], acc[i][2], acc[i][3]);
        *(float4*)(dst + (ty * 4 + i) * 64 + tx * 4) = v;
    }
}

__global__ __launch_bounds__(256) void k_redC(const float* __restrict__ pC, float* __restrict__ Tc)
{
    const int b = blockIdx.y;
    const int idx = blockIdx.x * 256 + threadIdx.x;
    const float* p = pC + (size_t)b * NKC * 4096 + idx;
    float acc = 0.f;
#pragma unroll
    for (int k = 0; k < NKC; k++) acc += p[(size_t)k * 4096];
    Tc[(size_t)b * 4096 + idx] = acc;
}

// softmax over c (rows) per column d; grid (NB), block 1024: 64 d-cols x 64 rows
__global__ __launch_bounds__(1024) void k_softC(float* __restrict__ Tc)
{
    __shared__ float red[16 * 65];
    const int b = blockIdx.x;
    const int t = threadIdx.x;
    const int dc = t & 63, cg = t >> 6;     // 16 row-groups x 4 rows
    float* S = Tc + (size_t)b * 4096 + dc;

    float v[4];
    float m = -3.4e38f;
#pragma unroll
    for (int j = 0; j < 4; j++) { v[j] = S[(cg * 4 + j) * 64]; m = fmaxf(m, v[j]); }
    red[cg * 65 + dc] = m;
    __syncthreads();
    for (int st = 8; st > 0; st >>= 1) {
        if (cg < st) red[cg * 65 + dc] = fmaxf(red[cg * 65 + dc], red[(cg + st) * 65 + dc]);
        __syncthreads();
    }
    m = red[dc];
    __syncthreads();
    float sum = 0.f;
#pragma unroll
    for (int j = 0; j < 4; j++) { v[j] = __expf(v[j] - m); sum += v[j]; }
    red[cg * 65 + dc] = sum;
    __syncthreads();
    for (int st = 8; st > 0; st >>= 1) {
        if (cg < st) red[cg * 65 + dc] += red[(cg + st) * 65 + dc];
        __syncthreads();
    }
    const float inv = 1.f / red[dc];
#pragma unroll
    for (int j = 0; j < 4; j++) S[(cg * 4 + j) * 64] = v[j] * inv;
}

// ---------------- Co: s_flat[b][n*64+d] = detal * sum_c inp[b,c,n]*Tc[c,d] ----------------
__global__ __launch_bounds__(256) void k_co(
    const float* __restrict__ inp, const float* __restrict__ Tc,
    const float* __restrict__ detal, float* __restrict__ s)
{
    __shared__ float tc[64 * 68];    // [c][d], stride 68
    __shared__ float xs[64 * 132];   // [c][n], stride 132
    const int b  = blockIdx.y;
    const int n0 = blockIdx.x * 128;
    const int t  = threadIdx.x;
    const int d4 = (t & 15) * 4;
    const int g8 = (t >> 4) * 8;

    {
        const int sr = t >> 2, sc = (t & 3) * 4;
        const float* src = inp + ((size_t)b * CC + sr) * NN + n0;
        float* dst = xs + sr * 132;
#pragma unroll
        for (int k = 0; k < 8; k++)
            *(float4*)(dst + sc + 16 * k) = *(const float4*)(src + sc + 16 * k);
        const float* tsrc = Tc + (size_t)b * 4096 + sr * 64;
        float* tdst = tc + sr * 68;
#pragma unroll
        for (int k = 0; k < 4; k++)
            *(float4*)(tdst + sc + 16 * k) = *(const float4*)(tsrc + sc + 16 * k);
    }
    __syncthreads();

    float acc[8][4];
#pragma unroll
    for (int i = 0; i < 8; i++)
#pragma unroll
        for (int j = 0; j < 4; j++) acc[i][j] = 0.f;

#pragma unroll 4
    for (int c = 0; c < 64; c++) {
        const float4 t4 = *(const float4*)(tc + c * 68 + d4);
        const float4 xa = *(const float4*)(xs + c * 132 + g8);
        const float4 xb = *(const float4*)(xs + c * 132 + g8 + 4);
        const float xv[8] = {xa.x, xa.y, xa.z, xa.w, xb.x, xb.y, xb.z, xb.w};
        const float tv[4] = {t4.x, t4.y, t4.z, t4.w};
#pragma unroll
        for (int i = 0; i < 8; i++)
#pragma unroll
            for (int j = 0; j < 4; j++) acc[i][j] += xv[i] * tv[j];
    }
    const float scl = detal[0];
    float* sb = s + (size_t)b * CC * NN + (size_t)n0 * 64;
#pragma unroll
    for (int i = 0; i < 8; i++) {
        float4 v = make_float4(acc[i][0] * scl, acc[i][1] * scl,
                               acc[i][2] * scl, acc[i][3] * scl);
        *(float4*)(sb + (size_t)(g8 + i) * 64 + d4) = v;
    }
}

// ---------------- Wo (==Ho): s[b,c,h,v] += 2*detal * sum_w inp[b,c,h,w]*Tw[w,v] ----------------
// grid (CC, 2, NB) = 1024 blocks, block 128 (2 waves). Tile 64h x 128v, 8x8/thread,
// K=128 in 4 chunks of 32. X staged transposed [w][h]; Tw staged [w][v].
__global__ __launch_bounds__(128) void k_wo(
    const float* __restrict__ inp, const float* __restrict__ Tw,
    const float* __restrict__ detal, float* __restrict__ s)
{
    __shared__ float xt[32 * 68];     // [w][h_local 64], stride 68
    __shared__ float twl[32 * 132];   // [w][v], stride 132
    const int b = blockIdx.z, hc = blockIdx.y, c = blockIdx.x;
    const int t = threadIdx.x;
    const int rg = t >> 4;            // 0..7 : h = rg*8..+8
    const int vg = t & 15;            // v cols: vg*4 and 64+vg*4
    const int h0 = hc * 64;

    const float* ip = inp + ((size_t)b * CC + c) * NN + (size_t)h0 * WW;
    const float* twg = Tw + (size_t)b * 16384;

    float acc[8][8];
#pragma unroll
    for (int p = 0; p < 8; p++)
#pragma unroll
        for (int q = 0; q < 8; q++) acc[p][q] = 0.f;

    for (int w0 = 0; w0 < 128; w0 += 32) {
        __syncthreads();
        {   // stage X^T: 64 h-rows, w-chunk 32; thread: h=t>>1, 16 w's (coalesced 64B/lane)
            const int h = t >> 1, wq = (t & 1) * 16;
            const float* src = ip + (size_t)h * WW + w0 + wq;
            float v[16];
            *(float4*)(v)      = *(const float4*)(src);
            *(float4*)(v + 4)  = *(const float4*)(src + 4);
            *(float4*)(v + 8)  = *(const float4*)(src + 8);
            *(float4*)(v + 12) = *(const float4*)(src + 12);
#pragma unroll
            for (int j = 0; j < 16; j++) xt[(wq + j) * 68 + h] = v[j];
        }
        {   // stage Tw rows: [w][v]; thread: w=t>>2, 32 v's
            const int w = t >> 2, cq = (t & 3) * 32;
            const float* src = twg + (size_t)(w0 + w) * 128 + cq;
            float* dst = twl + w * 132 + cq;
#pragma unroll
            for (int k = 0; k < 8; k++)
                *(float4*)(dst + 4 * k) = *(const float4*)(src + 4 * k);
        }
        __syncthreads();
#pragma unroll 4
        for (int w = 0; w < 32; ++w) {
            const float4 ra = *(const float4*)(xt + w * 68 + rg * 8);
            const float4 rb = *(const float4*)(xt + w * 68 + rg * 8 + 4);
            const float4 ta = *(const float4*)(twl + w * 132 + vg * 4);
            const float4 tb = *(const float4*)(twl + w * 132 + 64 + vg * 4);
            const float rv[8] = {ra.x, ra.y, ra.z, ra.w, rb.x, rb.y, rb.z, rb.w};
            const float tv[8] = {ta.x, ta.y, ta.z, ta.w, tb.x, tb.y, tb.z, tb.w};
#pragma unroll
            for (int p = 0; p < 8; p++)
#pragma unroll
                for (int q = 0; q < 8; q++) acc[p][q] += rv[p] * tv[q];
        }
    }

    const float sc2 = 2.0f * detal[0];
    float* sp = s + ((size_t)b * CC + c) * NN + (size_t)h0 * WW;
#pragma unroll
    for (int p = 0; p < 8; ++p) {
        const int h = rg * 8 + p;
        float* q0 = sp + (size_t)h * WW + vg * 4;
        float* q1 = sp + (size_t)h * WW + 64 + vg * 4;
        float4 c0 = *(const float4*)q0;
        float4 c1 = *(const float4*)q1;
        c0.x += sc2 * acc[p][0]; c0.y += sc2 * acc[p][1];
        c0.z += sc2 * acc[p][2]; c0.w += sc2 * acc[p][3];
        c1.x += sc2 * acc[p][4]; c1.y += sc2 * acc[p][5];
        c1.z += sc2 * acc[p][6]; c1.w += sc2 * acc[p][7];
        *(float4*)q0 = c0;
        *(float4*)q1 = c1;
    }
}

// ---------------- outconv: out[b,o,n] = sum_c w_out[o,c]*s[b,c,n] + b_out[o] + x[b,o,n] ----------------
// grid (NN/128, 4, NB), block 128 (2 waves). Same no-LDS direct-from-L1/L2 structure as
// k_inconv (see its comment); K=64, residual x fused in epilogue.
__global__ __launch_bounds__(128) void k_outconv(
    const float* __restrict__ s, const float* __restrict__ wot,
    const float* __restrict__ b_out, const float* __restrict__ x,
    float* __restrict__ outp)
{
    const int b  = blockIdx.z;
    const int o0 = blockIdx.y * 64;
    const int n0 = blockIdx.x * 128;
    const int t  = threadIdx.x;
    const int og = t >> 4;           // 0..7 : o = o0+og*8..+8
    const int ng = t & 15;           // n cols: n0+ng*4 and n0+64+ng*4

    float acc[8][8];
#pragma unroll
    for (int p = 0; p < 8; p++)
#pragma unroll
        for (int q = 0; q < 8; q++) acc[p][q] = 0.f;

    const float* sp = s + (size_t)b * CC * NN + n0 + ng * 4;
    const float* wp = wot + o0 + og * 8;

#pragma unroll 4
    for (int c = 0; c < CC; ++c) {
        const float4 sa = *(const float4*)(sp);
        const float4 sb = *(const float4*)(sp + 64);
        const float4 wa = *(const float4*)(wp);
        const float4 wb = *(const float4*)(wp + 4);
        sp += NN;
        wp += IC;
        const float wv[8] = {wa.x, wa.y, wa.z, wa.w, wb.x, wb.y, wb.z, wb.w};
        const float sv[8] = {sa.x, sa.y, sa.z, sa.w, sb.x, sb.y, sb.z, sb.w};
#pragma unroll
        for (int p = 0; p < 8; p++)
#pragma unroll
            for (int q = 0; q < 8; q++) acc[p][q] += wv[p] * sv[q];
    }

#pragma unroll
    for (int p = 0; p < 8; ++p) {
        const int oo = o0 + og * 8 + p;
        const float bo = b_out[oo];
        const float* xb = x + ((size_t)b * IC + oo) * NN + n0;
        float* ob = outp + ((size_t)b * IC + oo) * NN + n0;
        const float4 x0 = *(const float4*)(xb + ng * 4);
        const float4 x1 = *(const float4*)(xb + 64 + ng * 4);
        *(float4*)(ob + ng * 4) =
            make_float4(acc[p][0] + bo + x0.x, acc[p][1] + bo + x0.y,
                        acc[p][2] + bo + x0.z, acc[p][3] + bo + x0.w);
        *(float4*)(ob + 64 + ng * 4) =
            make_float4(acc[p][4] + bo + x1.x, acc[p][5] + bo + x1.y,
                        acc[p][6] + bo + x1.z, acc[p][7] + bo + x1.w);
    }
}

extern "C" void kernel_launch(void* const* d_in, const int* in_sizes, int n_in,
                              void* d_out, int out_size, void* d_ws, size_t ws_size,
                              hipStream_t stream)
{
    const float* x     = (const float*)d_in[0];
    const float* w_in  = (const float*)d_in[1];
    const float* b_in  = (const float*)d_in[2];
    const float* w_out = (const float*)d_in[3];
    const float* b_out = (const float*)d_in[4];
    const float* detal = (const float*)d_in[5];
    float* out = (float*)d_out;

    float* ws   = (float*)d_ws;
    float* inp  = ws + OFF_INP;
    float* s    = ws + OFF_S;
    float* pW   = ws + OFF_S;      // aliased with s (pW dead before k_co writes s)
    float* pC   = ws + OFF_PC;
    float* Tw   = ws + OFF_TW;
    float* Tc   = ws + OFF_TC;
    float* wt   = ws + OFF_WT;
    float* wot  = ws + OFF_WOT;

    k_wt     <<<dim3(128),              256, 0, stream>>>(w_in, w_out, wt, wot);
    k_inconv <<<dim3(NN / 128, NB),     128, 0, stream>>>(x, wt, b_in, inp);
    k_gramW  <<<dim3(NKW, NB),          256, 0, stream>>>(inp, pW);
    k_redW   <<<dim3(64, NB),           256, 0, stream>>>(pW, Tw);
    k_softW  <<<dim3(NB, 4),           1024, 0, stream>>>(Tw);
    k_gramC  <<<dim3(NKC, NB),          256, 0, stream>>>(inp, pC);
    k_redC   <<<dim3(16, NB),           256, 0, stream>>>(pC, Tc);
    k_softC  <<<dim3(NB),              1024, 0, stream>>>(Tc);
    k_co     <<<dim3(NN / 128, NB),     256, 0, stream>>>(inp, Tc, detal, s);
    k_wo     <<<dim3(CC, 2, NB),        128, 0, stream>>>(inp, Tw, detal, s);
    k_outconv<<<dim3(NN / 128, 4, NB),  128, 0, stream>>>(s, wot, b_out, x, out);
}

// Round 9
// 466.973 us; speedup vs baseline: 1.2682x; 1.2682x over previous
//
#include <hip/hip_runtime.h>
#include <math.h>

#define NB 8
#define IC 256
#define CC 64
#define HH 128
#define WW 128
#define NN (HH*WW)      // 16384
#define NKW 64          // k-chunks for gramW (8192/64 = 128 k per chunk)
#define NKC 64          // n-chunks for gramC (16384/64 = 256 n per chunk)

// ---------------- workspace layout (floats) ----------------
static constexpr size_t SZ_INP  = (size_t)NB * CC * NN;            // 8,388,608
static constexpr size_t OFF_INP = 0;
static constexpr size_t OFF_S   = OFF_INP + SZ_INP;                // s AND pW (aliased)
static constexpr size_t OFF_PC  = OFF_S + SZ_INP;                  // pC: NB*NKC*4096
static constexpr size_t OFF_TW  = OFF_PC + (size_t)NB * NKC * 4096;
static constexpr size_t OFF_TC  = OFF_TW + (size_t)NB * 16384;
static constexpr size_t OFF_WT  = OFF_TC + (size_t)NB * 4096;      // w_in_t [256 i][64 o]
static constexpr size_t OFF_WOT = OFF_WT + 16384;                  // w_out_t [64 c][256 o]

// async global->LDS, 16B per lane; LDS dest = wave-uniform base + lane*16 (linear),
// global src is per-lane. No VGPR round-trip -> no spill pressure (rounds 4/5 lesson).
__device__ __forceinline__ void g2l16(const float* g, float* l)
{
    __builtin_amdgcn_global_load_lds(
        (const __attribute__((address_space(1))) void*)g,
        (__attribute__((address_space(3))) void*)l,
        16, 0, 0);
}

// ---------------- tiny transpose of both weight matrices ----------------
__global__ __launch_bounds__(256) void k_wt(
    const float* __restrict__ w_in, const float* __restrict__ w_out,
    float* __restrict__ w_in_t, float* __restrict__ w_out_t)
{
    const int idx = blockIdx.x * 256 + threadIdx.x;   // 0..32767
    if (idx < 16384) {
        const int o = idx & 63, i = idx >> 6;         // w_in_t[i][o] = w_in[o][i]
        w_in_t[idx] = w_in[o * IC + i];
    } else {
        const int j = idx - 16384;
        const int o = j & 255, c = j >> 8;            // w_out_t[c][o] = w_out[o][c]
        w_out_t[j] = w_out[o * CC + c];
    }
}

// ---------------- inconv: inp[b,o,n] = sum_i w_in[o,i]*x[b,i,n] + b_in[o] ----------------
// grid (NN/256, NB), block 256. Tile 64o x 256n, 8x8/thread, K-chunk 16.
// ASYNC double-buffer: global_load_lds issues next chunk right after the barrier; the
// 16x64-FMA compute (2048 cy/wave) hides the ~600 cy load latency; the single
// __syncthreads per chunk (implicit vmcnt(0)) then drains at ~zero cost. This removes
// the synchronous stage-wait that pinned all LDS variants (rounds 0-7) at ~80us.
// LDS is unpadded-linear as global_load_lds requires; writes are HW-linear (no conflicts).
__global__ __launch_bounds__(256) void k_inconv(
    const float* __restrict__ x, const float* __restrict__ wt,
    const float* __restrict__ b_in, float* __restrict__ inp)
{
    __shared__ float xs[2][16 * 256];   // [buf][i][n], 32 KB
    __shared__ float wl[2][16 * 64];    // [buf][i][o], 8 KB
    const int b  = blockIdx.y;
    const int n0 = blockIdx.x * 256;
    const int t  = threadIdx.x;
    const int og = t >> 5;              // 0..7 : o = og*8..+8 (2 distinct/wave -> broadcast)
    const int ng = t & 31;              // n cols: ng*4 and 128+ng*4
    const int wv = t >> 6, ln = t & 63; // wave id / lane

    // per-wave staging bases: wave wv owns rows wv*4..wv*4+3 of each 16-row chunk
    const float* xg = x + ((size_t)b * IC + wv * 4) * NN + n0 + ln * 4;
    const float* wg = wt + (size_t)(wv * 4) * 64 + ln * 4;   // wt rows contiguous: 4 rows/load

    // prologue: stage chunk 0 into buf 0
#pragma unroll
    for (int k = 0; k < 4; ++k)
        g2l16(xg + (size_t)k * NN, &xs[0][(wv * 4 + k) * 256 + ln * 4]);
    g2l16(wg, &wl[0][wv * 4 * 64 + ln * 4]);

    float acc[8][8];
#pragma unroll
    for (int p = 0; p < 8; p++)
#pragma unroll
        for (int q = 0; q < 8; q++) acc[p][q] = 0.f;

    int cur = 0;
    for (int i0 = 0; i0 < IC; i0 += 16) {
        __syncthreads();               // drains buf[cur]'s loads (vmcnt 0) + syncs
        if (i0 + 16 < IC) {            // issue next chunk into buf[cur^1]
            const int nb = cur ^ 1;
            const float* xgn = xg + (size_t)(i0 + 16) * NN;
            const float* wgn = wg + (size_t)(i0 + 16) * 64;
#pragma unroll
            for (int k = 0; k < 4; ++k)
                g2l16(xgn + (size_t)k * NN, &xs[nb][(wv * 4 + k) * 256 + ln * 4]);
            g2l16(wgn, &wl[nb][wv * 4 * 64 + ln * 4]);
        }
        const float* xc = xs[cur];
        const float* wc = wl[cur];
#pragma unroll 4
        for (int i = 0; i < 16; ++i) {
            const float4 wa = *(const float4*)(wc + i * 64 + og * 8);
            const float4 wb = *(const float4*)(wc + i * 64 + og * 8 + 4);
            const float4 xa = *(const float4*)(xc + i * 256 + ng * 4);
            const float4 xb = *(const float4*)(xc + i * 256 + 128 + ng * 4);
            const float wv8[8] = {wa.x, wa.y, wa.z, wa.w, wb.x, wb.y, wb.z, wb.w};
            const float xv8[8] = {xa.x, xa.y, xa.z, xa.w, xb.x, xb.y, xb.z, xb.w};
#pragma unroll
            for (int p = 0; p < 8; p++)
#pragma unroll
                for (int q = 0; q < 8; q++) acc[p][q] += wv8[p] * xv8[q];
        }
        cur ^= 1;
    }

#pragma unroll
    for (int p = 0; p < 8; ++p) {
        const int oo = og * 8 + p;
        const float bo = b_in[oo];
        float* base = inp + ((size_t)b * CC + oo) * NN + n0;
        *(float4*)(base + ng * 4) =
            make_float4(acc[p][0] + bo, acc[p][1] + bo, acc[p][2] + bo, acc[p][3] + bo);
        *(float4*)(base + 128 + ng * 4) =
            make_float4(acc[p][4] + bo, acc[p][5] + bo, acc[p][6] + bo, acc[p][7] + bo);
    }
}

// ---------------- gram W partials ----------------
__global__ __launch_bounds__(256) void k_gramW(const float* __restrict__ inp, float* __restrict__ pW)
{
    __shared__ float xs[8 * 128];
    const int b = blockIdx.y, kc = blockIdx.x;
    const int t = threadIdx.x, tx = t & 15, ty = t >> 4;
    const float* Xb = inp + (size_t)b * CC * NN;
    const int k0 = kc * ((CC * HH) / NKW);   // 128 k per chunk

    float acc[8][8];
#pragma unroll
    for (int i = 0; i < 8; i++)
#pragma unroll
        for (int j = 0; j < 8; j++) acc[i][j] = 0.f;

    for (int kk = k0; kk < k0 + (CC * HH) / NKW; kk += 8) {
        __syncthreads();
        for (int idx = t; idx < 1024; idx += 256)
            xs[idx] = Xb[((size_t)kk + (idx >> 7)) * WW + (idx & 127)];
        __syncthreads();
#pragma unroll
        for (int k = 0; k < 8; k++) {
            const float* row = xs + k * 128;
            float4 t0 = *(const float4*)(row + ty * 8);
            float4 t1 = *(const float4*)(row + ty * 8 + 4);
            float4 u0 = *(const float4*)(row + tx * 8);
            float4 u1 = *(const float4*)(row + tx * 8 + 4);
            float av[8] = {t0.x, t0.y, t0.z, t0.w, t1.x, t1.y, t1.z, t1.w};
            float bv[8] = {u0.x, u0.y, u0.z, u0.w, u1.x, u1.y, u1.z, u1.w};
#pragma unroll
            for (int i = 0; i < 8; i++)
#pragma unroll
                for (int j = 0; j < 8; j++) acc[i][j] += av[i] * bv[j];
        }
    }
    float* dst = pW + ((size_t)b * NKW + kc) * 16384;
#pragma unroll
    for (int i = 0; i < 8; i++)
#pragma unroll
        for (int j = 0; j < 8; j += 4) {
            float4 v = make_float4(acc[i][j], acc[i][j + 1], acc[i][j + 2], acc[i][j + 3]);
            *(float4*)(dst + (ty * 8 + i) * 128 + tx * 8 + j) = v;
        }
}

__global__ __launch_bounds__(256) void k_redW(const float* __restrict__ pW, float* __restrict__ Tw)
{
    const int b = blockIdx.y;
    const int idx = blockIdx.x * 256 + threadIdx.x;
    const float* p = pW + (size_t)b * NKW * 16384 + idx;
    float acc = 0.f;
#pragma unroll
    for (int k = 0; k < NKW; k++) acc += p[(size_t)k * 16384];
    Tw[(size_t)b * 16384 + idx] = acc;
}

// softmax over w (rows) per column v; grid (NB, 4), block 1024: 32 v-cols x 128 rows
__global__ __launch_bounds__(1024) void k_softW(float* __restrict__ Tw)
{
    __shared__ float red[32 * 33];
    const int b = blockIdx.x, v0 = blockIdx.y * 32;
    const int t = threadIdx.x;
    const int vc = t & 31, wg = t >> 5;      // 32 row-groups x 4 rows
    float* S = Tw + (size_t)b * 16384 + v0 + vc;

    float v[4];
    float m = -3.4e38f;
#pragma unroll
    for (int j = 0; j < 4; j++) { v[j] = S[(wg * 4 + j) * 128]; m = fmaxf(m, v[j]); }
    red[wg * 33 + vc] = m;
    __syncthreads();
    for (int st = 16; st > 0; st >>= 1) {
        if (wg < st) red[wg * 33 + vc] = fmaxf(red[wg * 33 + vc], red[(wg + st) * 33 + vc]);
        __syncthreads();
    }
    m = red[vc];
    __syncthreads();
    float sum = 0.f;
#pragma unroll
    for (int j = 0; j < 4; j++) { v[j] = __expf(v[j] - m); sum += v[j]; }
    red[wg * 33 + vc] = sum;
    __syncthreads();
    for (int st = 16; st > 0; st >>= 1) {
        if (wg < st) red[wg * 33 + vc] += red[(wg + st) * 33 + vc];
        __syncthreads();
    }
    const float inv = 1.f / red[vc];
#pragma unroll
    for (int j = 0; j < 4; j++) S[(wg * 4 + j) * 128] = v[j] * inv;
}

// ---------------- gram C partials: transposed LDS tile [n][c] ----------------
__global__ __launch_bounds__(256) void k_gramC(const float* __restrict__ inp, float* __restrict__ pC)
{
    __shared__ float xt[32 * 68];   // [n_local][c], stride 68
    const int b = blockIdx.y, nc = blockIdx.x;
    const int t = threadIdx.x, tx = t & 15, ty = t >> 4;
    const float* ip = inp + (size_t)b * CC * NN;
    const int n0 = nc * (NN / NKC);

    float acc[4][4];
#pragma unroll
    for (int i = 0; i < 4; i++)
#pragma unroll
        for (int j = 0; j < 4; j++) acc[i][j] = 0.f;

    const int scc = t >> 2;
    const int sn  = (t & 3) * 8;

    for (int nt = 0; nt < NN / NKC; nt += 32) {
        __syncthreads();
        {
            const float* src = ip + (size_t)scc * NN + n0 + nt + sn;
            float v[8];
            *(float4*)(v)     = *(const float4*)(src);
            *(float4*)(v + 4) = *(const float4*)(src + 4);
#pragma unroll
            for (int j = 0; j < 8; j++) xt[(sn + j) * 68 + scc] = v[j];
        }
        __syncthreads();
#pragma unroll 8
        for (int nn = 0; nn < 32; nn++) {
            const float4 a4 = *(const float4*)(xt + nn * 68 + ty * 4);
            const float4 e4 = *(const float4*)(xt + nn * 68 + tx * 4);
            const float av[4] = {a4.x, a4.y, a4.z, a4.w};
            const float ev[4] = {e4.x, e4.y, e4.z, e4.w};
#pragma unroll
            for (int i = 0; i < 4; i++)
#pragma unroll
                for (int j = 0; j < 4; j++) acc[i][j] += av[i] * ev[j];
        }
    }
    float* dst = pC + ((size_t)b * NKC + nc) * 4096;
#pragma unroll
    for (int i = 0; i < 4; i++) {
        float4 v = make_float4(acc[i][0], acc[i][1], acc[i][2], acc[i][3]);
        *(float4*)(dst + (ty * 4 + i) * 64 + tx * 4) = v;
    }
}

__global__ __launch_bounds__(256) void k_redC(const float* __restrict__ pC, float* __restrict__ Tc)
{
    const int b = blockIdx.y;
    const int idx = blockIdx.x * 256 + threadIdx.x;
    const float* p = pC + (size_t)b * NKC * 4096 + idx;
    float acc = 0.f;
#pragma unroll
    for (int k = 0; k < NKC; k++) acc += p[(size_t)k * 4096];
    Tc[(size_t)b * 4096 + idx] = acc;
}

// softmax over c (rows) per column d; grid (NB), block 1024: 64 d-cols x 64 rows
__global__ __launch_bounds__(1024) void k_softC(float* __restrict__ Tc)
{
    __shared__ float red[16 * 65];
    const int b = blockIdx.x;
    const int t = threadIdx.x;
    const int dc = t & 63, cg = t >> 6;     // 16 row-groups x 4 rows
    float* S = Tc + (size_t)b * 4096 + dc;

    float v[4];
    float m = -3.4e38f;
#pragma unroll
    for (int j = 0; j < 4; j++) { v[j] = S[(cg * 4 + j) * 64]; m = fmaxf(m, v[j]); }
    red[cg * 65 + dc] = m;
    __syncthreads();
    for (int st = 8; st > 0; st >>= 1) {
        if (cg < st) red[cg * 65 + dc] = fmaxf(red[cg * 65 + dc], red[(cg + st) * 65 + dc]);
        __syncthreads();
    }
    m = red[dc];
    __syncthreads();
    float sum = 0.f;
#pragma unroll
    for (int j = 0; j < 4; j++) { v[j] = __expf(v[j] - m); sum += v[j]; }
    red[cg * 65 + dc] = sum;
    __syncthreads();
    for (int st = 8; st > 0; st >>= 1) {
        if (cg < st) red[cg * 65 + dc] += red[(cg + st) * 65 + dc];
        __syncthreads();
    }
    const float inv = 1.f / red[dc];
#pragma unroll
    for (int j = 0; j < 4; j++) S[(cg * 4 + j) * 64] = v[j] * inv;
}

// ---------------- Co: s_flat[b][n*64+d] = detal * sum_c inp[b,c,n]*Tc[c,d] ----------------
__global__ __launch_bounds__(256) void k_co(
    const float* __restrict__ inp, const float* __restrict__ Tc,
    const float* __restrict__ detal, float* __restrict__ s)
{
    __shared__ float tc[64 * 68];    // [c][d], stride 68
    __shared__ float xs[64 * 132];   // [c][n], stride 132
    const int b  = blockIdx.y;
    const int n0 = blockIdx.x * 128;
    const int t  = threadIdx.x;
    const int d4 = (t & 15) * 4;
    const int g8 = (t >> 4) * 8;

    {
        const int sr = t >> 2, sc = (t & 3) * 4;
        const float* src = inp + ((size_t)b * CC + sr) * NN + n0;
        float* dst = xs + sr * 132;
#pragma unroll
        for (int k = 0; k < 8; k++)
            *(float4*)(dst + sc + 16 * k) = *(const float4*)(src + sc + 16 * k);
        const float* tsrc = Tc + (size_t)b * 4096 + sr * 64;
        float* tdst = tc + sr * 68;
#pragma unroll
        for (int k = 0; k < 4; k++)
            *(float4*)(tdst + sc + 16 * k) = *(const float4*)(tsrc + sc + 16 * k);
    }
    __syncthreads();

    float acc[8][4];
#pragma unroll
    for (int i = 0; i < 8; i++)
#pragma unroll
        for (int j = 0; j < 4; j++) acc[i][j] = 0.f;

#pragma unroll 4
    for (int c = 0; c < 64; c++) {
        const float4 t4 = *(const float4*)(tc + c * 68 + d4);
        const float4 xa = *(const float4*)(xs + c * 132 + g8);
        const float4 xb = *(const float4*)(xs + c * 132 + g8 + 4);
        const float xv[8] = {xa.x, xa.y, xa.z, xa.w, xb.x, xb.y, xb.z, xb.w};
        const float tv[4] = {t4.x, t4.y, t4.z, t4.w};
#pragma unroll
        for (int i = 0; i < 8; i++)
#pragma unroll
            for (int j = 0; j < 4; j++) acc[i][j] += xv[i] * tv[j];
    }
    const float scl = detal[0];
    float* sb = s + (size_t)b * CC * NN + (size_t)n0 * 64;
#pragma unroll
    for (int i = 0; i < 8; i++) {
        float4 v = make_float4(acc[i][0] * scl, acc[i][1] * scl,
                               acc[i][2] * scl, acc[i][3] * scl);
        *(float4*)(sb + (size_t)(g8 + i) * 64 + d4) = v;
    }
}

// ---------------- Wo (==Ho): s[b,c,h,v] += 2*detal * sum_w inp[b,c,h,w]*Tw[w,v] ----------------
// grid (CC, NB), block 256. Tile 128h x 128v, 8x8 per thread, K=128 in 4 chunks of 32.
// X staged transposed [w][h] (stride 132); Tw staged [w][v] (stride 132). (round-6 version)
__global__ __launch_bounds__(256, 2) void k_wo(
    const float* __restrict__ inp, const float* __restrict__ Tw,
    const float* __restrict__ detal, float* __restrict__ s)
{
    __shared__ float xt[32 * 132];    // [w][h]
    __shared__ float twl[32 * 132];   // [w][v]
    const int b = blockIdx.y, c = blockIdx.x;
    const int t = threadIdx.x;
    const int rg = t >> 4;            // 0..15 : h = rg*8..+8
    const int vg = t & 15;            // v cols: vg*4 and 64+vg*4

    const float* ip = inp + ((size_t)b * CC + c) * NN;
    const float* twg = Tw + (size_t)b * 16384;

    float acc[8][8];
#pragma unroll
    for (int p = 0; p < 8; p++)
#pragma unroll
        for (int q = 0; q < 8; q++) acc[p][q] = 0.f;

    for (int w0 = 0; w0 < 128; w0 += 32) {
        __syncthreads();
        {   // stage X^T: rows h=0..127, w-chunk 32; thread: h=t>>1, 16 w's
            const int h = t >> 1, wq = (t & 1) * 16;
            const float* src = ip + (size_t)h * WW + w0 + wq;
            float v[16];
            *(float4*)(v)      = *(const float4*)(src);
            *(float4*)(v + 4)  = *(const float4*)(src + 4);
            *(float4*)(v + 8)  = *(const float4*)(src + 8);
            *(float4*)(v + 12) = *(const float4*)(src + 12);
#pragma unroll
            for (int j = 0; j < 16; j++) xt[(wq + j) * 132 + h] = v[j];
        }
        {   // stage Tw rows: [w][v]; thread: w=t>>3, 16 v's
            const int w = t >> 3, cq = (t & 7) * 16;
            const float* src = twg + (size_t)(w0 + w) * 128 + cq;
            float* dst = twl + w * 132 + cq;
#pragma unroll
            for (int k = 0; k < 4; k++)
                *(float4*)(dst + 4 * k) = *(const float4*)(src + 4 * k);
        }
        __syncthreads();
#pragma unroll 4
        for (int w = 0; w < 32; ++w) {
            const float4 ra = *(const float4*)(xt + w * 132 + rg * 8);
            const float4 rb = *(const float4*)(xt + w * 132 + rg * 8 + 4);
            const float4 ta = *(const float4*)(twl + w * 132 + vg * 4);
            const float4 tb = *(const float4*)(twl + w * 132 + 64 + vg * 4);
            const float rv[8] = {ra.x, ra.y, ra.z, ra.w, rb.x, rb.y, rb.z, rb.w};
            const float tv[8] = {ta.x, ta.y, ta.z, ta.w, tb.x, tb.y, tb.z, tb.w};
#pragma unroll
            for (int p = 0; p < 8; p++)
#pragma unroll
                for (int q = 0; q < 8; q++) acc[p][q] += rv[p] * tv[q];
        }
    }

    const float sc2 = 2.0f * detal[0];
    float* sp = s + ((size_t)b * CC + c) * NN;
#pragma unroll
    for (int p = 0; p < 8; ++p) {
        const int h = rg * 8 + p;
        float* q0 = sp + (size_t)h * WW + vg * 4;
        float* q1 = sp + (size_t)h * WW + 64 + vg * 4;
        float4 c0 = *(const float4*)q0;
        float4 c1 = *(const float4*)q1;
        c0.x += sc2 * acc[p][0]; c0.y += sc2 * acc[p][1];
        c0.z += sc2 * acc[p][2]; c0.w += sc2 * acc[p][3];
        c1.x += sc2 * acc[p][4]; c1.y += sc2 * acc[p][5];
        c1.z += sc2 * acc[p][6]; c1.w += sc2 * acc[p][7];
        *(float4*)q0 = c0;
        *(float4*)q1 = c1;
    }
}

// ---------------- outconv: out[b,o,n] = sum_c w_out[o,c]*s[b,c,n] + b_out[o] + x[b,o,n] ----------------
// grid (NN/256, 4, NB), block 256. Same async double-buffer structure as k_inconv;
// K=64 in 4 chunks of 16. wot's 64-wide o-slice is non-contiguous across rows, so the
// wave-load uses per-lane global scatter (row = ln>>4, col = (ln&15)*4) with linear LDS.
__global__ __launch_bounds__(256) void k_outconv(
    const float* __restrict__ s, const float* __restrict__ wot,
    const float* __restrict__ b_out, const float* __restrict__ x,
    float* __restrict__ outp)
{
    __shared__ float ss[2][16 * 256];   // [buf][c][n], 32 KB
    __shared__ float wl[2][16 * 64];    // [buf][c][o_local], 8 KB
    const int b  = blockIdx.z;
    const int o0 = blockIdx.y * 64;
    const int n0 = blockIdx.x * 256;
    const int t  = threadIdx.x;
    const int og = t >> 5;
    const int ng = t & 31;
    const int wv = t >> 6, ln = t & 63;

    const float* sg = s + ((size_t)b * CC + wv * 4) * NN + n0 + ln * 4;
    const float* wg = wot + (size_t)(wv * 4 + (ln >> 4)) * IC + o0 + (ln & 15) * 4;

    // prologue: stage chunk 0 into buf 0
#pragma unroll
    for (int k = 0; k < 4; ++k)
        g2l16(sg + (size_t)k * NN, &ss[0][(wv * 4 + k) * 256 + ln * 4]);
    g2l16(wg, &wl[0][wv * 4 * 64 + ln * 4]);

    float acc[8][8];
#pragma unroll
    for (int p = 0; p < 8; p++)
#pragma unroll
        for (int q = 0; q < 8; q++) acc[p][q] = 0.f;

    int cur = 0;
    for (int c0 = 0; c0 < CC; c0 += 16) {
        __syncthreads();
        if (c0 + 16 < CC) {
            const int nb = cur ^ 1;
            const float* sgn = sg + (size_t)(c0 + 16) * NN;
            const float* wgn = wg + (size_t)(c0 + 16) * IC;
#pragma unroll
            for (int k = 0; k < 4; ++k)
                g2l16(sgn + (size_t)k * NN, &ss[nb][(wv * 4 + k) * 256 + ln * 4]);
            g2l16(wgn, &wl[nb][wv * 4 * 64 + ln * 4]);
        }
        const float* sc = ss[cur];
        const float* wc = wl[cur];
#pragma unroll 4
        for (int c = 0; c < 16; ++c) {
            const float4 wa = *(const float4*)(wc + c * 64 + og * 8);
            const float4 wb = *(const float4*)(wc + c * 64 + og * 8 + 4);
            const float4 sa = *(const float4*)(sc + c * 256 + ng * 4);
            const float4 sb = *(const float4*)(sc + c * 256 + 128 + ng * 4);
            const float wv8[8] = {wa.x, wa.y, wa.z, wa.w, wb.x, wb.y, wb.z, wb.w};
            const float sv8[8] = {sa.x, sa.y, sa.z, sa.w, sb.x, sb.y, sb.z, sb.w};
#pragma unroll
            for (int p = 0; p < 8; p++)
#pragma unroll
                for (int q = 0; q < 8; q++) acc[p][q] += wv8[p] * sv8[q];
        }
        cur ^= 1;
    }

#pragma unroll
    for (int p = 0; p < 8; ++p) {
        const int oo = o0 + og * 8 + p;
        const float bo = b_out[oo];
        const float* xb = x + ((size_t)b * IC + oo) * NN + n0;
        float* ob = outp + ((size_t)b * IC + oo) * NN + n0;
        const float4 x0 = *(const float4*)(xb + ng * 4);
        const float4 x1 = *(const float4*)(xb + 128 + ng * 4);
        *(float4*)(ob + ng * 4) =
            make_float4(acc[p][0] + bo + x0.x, acc[p][1] + bo + x0.y,
                        acc[p][2] + bo + x0.z, acc[p][3] + bo + x0.w);
        *(float4*)(ob + 128 + ng * 4) =
            make_float4(acc[p][4] + bo + x1.x, acc[p][5] + bo + x1.y,
                        acc[p][6] + bo + x1.z, acc[p][7] + bo + x1.w);
    }
}

extern "C" void kernel_launch(void* const* d_in, const int* in_sizes, int n_in,
                              void* d_out, int out_size, void* d_ws, size_t ws_size,
                              hipStream_t stream)
{
    const float* x     = (const float*)d_in[0];
    const float* w_in  = (const float*)d_in[1];
    const float* b_in  = (const float*)d_in[2];
    const float* w_out = (const float*)d_in[3];
    const float* b_out = (const float*)d_in[4];
    const float* detal = (const float*)d_in[5];
    float* out = (float*)d_out;

    float* ws   = (float*)d_ws;
    float* inp  = ws + OFF_INP;
    float* s    = ws + OFF_S;
    float* pW   = ws + OFF_S;      // aliased with s (pW dead before k_co writes s)
    float* pC   = ws + OFF_PC;
    float* Tw   = ws + OFF_TW;
    float* Tc   = ws + OFF_TC;
    float* wt   = ws + OFF_WT;
    float* wot  = ws + OFF_WOT;

    k_wt     <<<dim3(128),              256, 0, stream>>>(w_in, w_out, wt, wot);
    k_inconv <<<dim3(NN / 256, NB),     256, 0, stream>>>(x, wt, b_in, inp);
    k_gramW  <<<dim3(NKW, NB),          256, 0, stream>>>(inp, pW);
    k_redW   <<<dim3(64, NB),           256, 0, stream>>>(pW, Tw);
    k_softW  <<<dim3(NB, 4),           1024, 0, stream>>>(Tw);
    k_gramC  <<<dim3(NKC, NB),          256, 0, stream>>>(inp, pC);
    k_redC   <<<dim3(16, NB),           256, 0, stream>>>(pC, Tc);
    k_softC  <<<dim3(NB),              1024, 0, stream>>>(Tc);
    k_co     <<<dim3(NN / 128, NB),     256, 0, stream>>>(inp, Tc, detal, s);
    k_wo     <<<dim3(CC, NB),           256, 0, stream>>>(inp, Tw, detal, s);
    k_outconv<<<dim3(NN / 256, 4, NB),  256, 0, stream>>>(s, wot, b_out, x, out);
}

// Round 10
// 444.389 us; speedup vs baseline: 1.3326x; 1.0508x over previous
//
#include <hip/hip_runtime.h>
#include <math.h>

#define NB 8
#define IC 256
#define CC 64
#define HH 128
#define WW 128
#define NN (HH*WW)      // 16384
#define NKW 64          // k-chunks for gramW (8192/64 = 128 k per chunk)
#define NKC 64          // n-chunks for gramC (16384/64 = 256 n per chunk)

// ---------------- workspace layout (floats) ----------------
static constexpr size_t SZ_INP  = (size_t)NB * CC * NN;            // 8,388,608
static constexpr size_t OFF_INP = 0;
static constexpr size_t OFF_S   = OFF_INP + SZ_INP;                // s AND pW (aliased)
static constexpr size_t OFF_PC  = OFF_S + SZ_INP;                  // pC: NB*NKC*4096
static constexpr size_t OFF_TW  = OFF_PC + (size_t)NB * NKC * 4096;
static constexpr size_t OFF_TC  = OFF_TW + (size_t)NB * 16384;
static constexpr size_t OFF_WT  = OFF_TC + (size_t)NB * 4096;      // w_in_t [256 i][64 o]
static constexpr size_t OFF_WOT = OFF_WT + 16384;                  // w_out_t [64 c][256 o]

// ---------------- tiny transpose of both weight matrices ----------------
__global__ __launch_bounds__(256) void k_wt(
    const float* __restrict__ w_in, const float* __restrict__ w_out,
    float* __restrict__ w_in_t, float* __restrict__ w_out_t)
{
    const int idx = blockIdx.x * 256 + threadIdx.x;   // 0..32767
    if (idx < 16384) {
        const int o = idx & 63, i = idx >> 6;         // w_in_t[i][o] = w_in[o][i]
        w_in_t[idx] = w_in[o * IC + i];
    } else {
        const int j = idx - 16384;
        const int o = j & 255, c = j >> 8;            // w_out_t[c][o] = w_out[o][c]
        w_out_t[j] = w_out[o * CC + c];
    }
}

// ---------------- inconv: inp[b,o,n] = sum_i w_in[o,i]*x[b,i,n] + b_in[o] ----------------
// grid (NN/256, NB), block 256. Tile 64o x 256n, 8x8/thread, K-chunk 16 (round-6 version).
// LEDGER: every LDS-staged schedule (sync r0/1/3/6/7, 2-wave r7, async-dbuf r9) = 80us;
// no-LDS = 166us (r2/r8); reg-prefetch spills (r4/5). Structural wall: 8x8 tile -> only
// 8 waves/CU at this problem size; LDS-BW ceiling 66% duty = 41us, latency chains give
// ~40% = 80us. Past it needs split-K + reduce (+16us HBM) — poor ROI. Leave at 80.
__global__ __launch_bounds__(256) void k_inconv(
    const float* __restrict__ x, const float* __restrict__ wt,
    const float* __restrict__ b_in, float* __restrict__ inp)
{
    __shared__ float xs[16 * 260];   // [i][n], stride 260
    __shared__ float wl[16 * 68];    // [i][o], stride 68
    const int b  = blockIdx.y;
    const int n0 = blockIdx.x * 256;
    const int t  = threadIdx.x;
    const int og = t >> 5;           // 0..7 : o = og*8..+8
    const int ng = t & 31;           // n cols: n0+ng*4 and n0+128+ng*4

    const int sr = t >> 4, sc = (t & 15) * 4;
    const float* xbase = x + ((size_t)b * IC + sr) * NN + n0 + sc;
    const float* wbase = wt + (size_t)sr * 64 + sc;
    float* xdst = xs + sr * 260 + sc;
    float* wdst = wl + sr * 68 + sc;

    float acc[8][8];
#pragma unroll
    for (int p = 0; p < 8; p++)
#pragma unroll
        for (int q = 0; q < 8; q++) acc[p][q] = 0.f;

    for (int i0 = 0; i0 < IC; i0 += 16) {
        __syncthreads();
        {
            const float* xsrc = xbase + (size_t)i0 * NN;
            const float4 a0 = *(const float4*)(xsrc);
            const float4 a1 = *(const float4*)(xsrc + 64);
            const float4 a2 = *(const float4*)(xsrc + 128);
            const float4 a3 = *(const float4*)(xsrc + 192);
            const float4 w0 = *(const float4*)(wbase + (size_t)i0 * 64);
            *(float4*)(xdst)       = a0;
            *(float4*)(xdst + 64)  = a1;
            *(float4*)(xdst + 128) = a2;
            *(float4*)(xdst + 192) = a3;
            *(float4*)(wdst)       = w0;
        }
        __syncthreads();
#pragma unroll 4
        for (int i = 0; i < 16; ++i) {
            const float4 wa = *(const float4*)(wl + i * 68 + og * 8);
            const float4 wb = *(const float4*)(wl + i * 68 + og * 8 + 4);
            const float4 xa = *(const float4*)(xs + i * 260 + ng * 4);
            const float4 xb = *(const float4*)(xs + i * 260 + 128 + ng * 4);
            const float wv[8] = {wa.x, wa.y, wa.z, wa.w, wb.x, wb.y, wb.z, wb.w};
            const float xv[8] = {xa.x, xa.y, xa.z, xa.w, xb.x, xb.y, xb.z, xb.w};
#pragma unroll
            for (int p = 0; p < 8; p++)
#pragma unroll
                for (int q = 0; q < 8; q++) acc[p][q] += wv[p] * xv[q];
        }
    }
#pragma unroll
    for (int p = 0; p < 8; ++p) {
        const int oo = og * 8 + p;
        const float bo = b_in[oo];
        float* base = inp + ((size_t)b * CC + oo) * NN + n0;
        *(float4*)(base + ng * 4) =
            make_float4(acc[p][0] + bo, acc[p][1] + bo, acc[p][2] + bo, acc[p][3] + bo);
        *(float4*)(base + 128 + ng * 4) =
            make_float4(acc[p][4] + bo, acc[p][5] + bo, acc[p][6] + bo, acc[p][7] + bo);
    }
}

// ---------------- gram W partials: K-chunk 32 (was 8), vectorized padded staging ----------------
__global__ __launch_bounds__(256) void k_gramW(const float* __restrict__ inp, float* __restrict__ pW)
{
    __shared__ float xs[32 * 132];   // [k][w], stride 132 (pad), 16.9 KB
    const int b = blockIdx.y, kc = blockIdx.x;
    const int t = threadIdx.x, tx = t & 15, ty = t >> 4;
    const float* Xb = inp + (size_t)b * CC * NN;
    const int k0 = kc * ((CC * HH) / NKW);   // 128 k per chunk

    float acc[8][8];
#pragma unroll
    for (int i = 0; i < 8; i++)
#pragma unroll
        for (int j = 0; j < 8; j++) acc[i][j] = 0.f;

    for (int kk = k0; kk < k0 + (CC * HH) / NKW; kk += 32) {
        __syncthreads();
        {   // 32 rows x 128: 8 threads/row x 16 floats, float4-vectorized
            const int r = t >> 3, cq = (t & 7) * 16;
            const float* src = Xb + ((size_t)kk + r) * WW + cq;
            float* dst = xs + r * 132 + cq;
#pragma unroll
            for (int j = 0; j < 4; j++)
                *(float4*)(dst + 4 * j) = *(const float4*)(src + 4 * j);
        }
        __syncthreads();
#pragma unroll 8
        for (int k = 0; k < 32; k++) {
            const float* row = xs + k * 132;
            float4 t0 = *(const float4*)(row + ty * 8);
            float4 t1 = *(const float4*)(row + ty * 8 + 4);
            float4 u0 = *(const float4*)(row + tx * 8);
            float4 u1 = *(const float4*)(row + tx * 8 + 4);
            float av[8] = {t0.x, t0.y, t0.z, t0.w, t1.x, t1.y, t1.z, t1.w};
            float bv[8] = {u0.x, u0.y, u0.z, u0.w, u1.x, u1.y, u1.z, u1.w};
#pragma unroll
            for (int i = 0; i < 8; i++)
#pragma unroll
                for (int j = 0; j < 8; j++) acc[i][j] += av[i] * bv[j];
        }
    }
    float* dst = pW + ((size_t)b * NKW + kc) * 16384;
#pragma unroll
    for (int i = 0; i < 8; i++)
#pragma unroll
        for (int j = 0; j < 8; j += 4) {
            float4 v = make_float4(acc[i][j], acc[i][j + 1], acc[i][j + 2], acc[i][j + 3]);
            *(float4*)(dst + (ty * 8 + i) * 128 + tx * 8 + j) = v;
        }
}

__global__ __launch_bounds__(256) void k_redW(const float* __restrict__ pW, float* __restrict__ Tw)
{
    const int b = blockIdx.y;
    const int idx = blockIdx.x * 256 + threadIdx.x;
    const float* p = pW + (size_t)b * NKW * 16384 + idx;
    float acc = 0.f;
#pragma unroll
    for (int k = 0; k < NKW; k++) acc += p[(size_t)k * 16384];
    Tw[(size_t)b * 16384 + idx] = acc;
}

// softmax over w (rows) per column v; grid (NB, 4), block 1024: 32 v-cols x 128 rows
__global__ __launch_bounds__(1024) void k_softW(float* __restrict__ Tw)
{
    __shared__ float red[32 * 33];
    const int b = blockIdx.x, v0 = blockIdx.y * 32;
    const int t = threadIdx.x;
    const int vc = t & 31, wg = t >> 5;      // 32 row-groups x 4 rows
    float* S = Tw + (size_t)b * 16384 + v0 + vc;

    float v[4];
    float m = -3.4e38f;
#pragma unroll
    for (int j = 0; j < 4; j++) { v[j] = S[(wg * 4 + j) * 128]; m = fmaxf(m, v[j]); }
    red[wg * 33 + vc] = m;
    __syncthreads();
    for (int st = 16; st > 0; st >>= 1) {
        if (wg < st) red[wg * 33 + vc] = fmaxf(red[wg * 33 + vc], red[(wg + st) * 33 + vc]);
        __syncthreads();
    }
    m = red[vc];
    __syncthreads();
    float sum = 0.f;
#pragma unroll
    for (int j = 0; j < 4; j++) { v[j] = __expf(v[j] - m); sum += v[j]; }
    red[wg * 33 + vc] = sum;
    __syncthreads();
    for (int st = 16; st > 0; st >>= 1) {
        if (wg < st) red[wg * 33 + vc] += red[(wg + st) * 33 + vc];
        __syncthreads();
    }
    const float inv = 1.f / red[vc];
#pragma unroll
    for (int j = 0; j < 4; j++) S[(wg * 4 + j) * 128] = v[j] * inv;
}

// ---------------- gram C partials: transposed LDS tile [n][c] ----------------
__global__ __launch_bounds__(256) void k_gramC(const float* __restrict__ inp, float* __restrict__ pC)
{
    __shared__ float xt[32 * 68];   // [n_local][c], stride 68
    const int b = blockIdx.y, nc = blockIdx.x;
    const int t = threadIdx.x, tx = t & 15, ty = t >> 4;
    const float* ip = inp + (size_t)b * CC * NN;
    const int n0 = nc * (NN / NKC);

    float acc[4][4];
#pragma unroll
    for (int i = 0; i < 4; i++)
#pragma unroll
        for (int j = 0; j < 4; j++) acc[i][j] = 0.f;

    const int scc = t >> 2;
    const int sn  = (t & 3) * 8;

    for (int nt = 0; nt < NN / NKC; nt += 32) {
        __syncthreads();
        {
            const float* src = ip + (size_t)scc * NN + n0 + nt + sn;
            float v[8];
            *(float4*)(v)     = *(const float4*)(src);
            *(float4*)(v + 4) = *(const float4*)(src + 4);
#pragma unroll
            for (int j = 0; j < 8; j++) xt[(sn + j) * 68 + scc] = v[j];
        }
        __syncthreads();
#pragma unroll 8
        for (int nn = 0; nn < 32; nn++) {
            const float4 a4 = *(const float4*)(xt + nn * 68 + ty * 4);
            const float4 e4 = *(const float4*)(xt + nn * 68 + tx * 4);
            const float av[4] = {a4.x, a4.y, a4.z, a4.w};
            const float ev[4] = {e4.x, e4.y, e4.z, e4.w};
#pragma unroll
            for (int i = 0; i < 4; i++)
#pragma unroll
                for (int j = 0; j < 4; j++) acc[i][j] += av[i] * ev[j];
        }
    }
    float* dst = pC + ((size_t)b * NKC + nc) * 4096;
#pragma unroll
    for (int i = 0; i < 4; i++) {
        float4 v = make_float4(acc[i][0], acc[i][1], acc[i][2], acc[i][3]);
        *(float4*)(dst + (ty * 4 + i) * 64 + tx * 4) = v;
    }
}

__global__ __launch_bounds__(256) void k_redC(const float* __restrict__ pC, float* __restrict__ Tc)
{
    const int b = blockIdx.y;
    const int idx = blockIdx.x * 256 + threadIdx.x;
    const float* p = pC + (size_t)b * NKC * 4096 + idx;
    float acc = 0.f;
#pragma unroll
    for (int k = 0; k < NKC; k++) acc += p[(size_t)k * 4096];
    Tc[(size_t)b * 4096 + idx] = acc;
}

// softmax over c (rows) per column d; grid (NB), block 1024: 64 d-cols x 64 rows
__global__ __launch_bounds__(1024) void k_softC(float* __restrict__ Tc)
{
    __shared__ float red[16 * 65];
    const int b = blockIdx.x;
    const int t = threadIdx.x;
    const int dc = t & 63, cg = t >> 6;     // 16 row-groups x 4 rows
    float* S = Tc + (size_t)b * 4096 + dc;

    float v[4];
    float m = -3.4e38f;
#pragma unroll
    for (int j = 0; j < 4; j++) { v[j] = S[(cg * 4 + j) * 64]; m = fmaxf(m, v[j]); }
    red[cg * 65 + dc] = m;
    __syncthreads();
    for (int st = 8; st > 0; st >>= 1) {
        if (cg < st) red[cg * 65 + dc] = fmaxf(red[cg * 65 + dc], red[(cg + st) * 65 + dc]);
        __syncthreads();
    }
    m = red[dc];
    __syncthreads();
    float sum = 0.f;
#pragma unroll
    for (int j = 0; j < 4; j++) { v[j] = __expf(v[j] - m); sum += v[j]; }
    red[cg * 65 + dc] = sum;
    __syncthreads();
    for (int st = 8; st > 0; st >>= 1) {
        if (cg < st) red[cg * 65 + dc] += red[(cg + st) * 65 + dc];
        __syncthreads();
    }
    const float inv = 1.f / red[dc];
#pragma unroll
    for (int j = 0; j < 4; j++) S[(cg * 4 + j) * 64] = v[j] * inv;
}

// ---------------- Co: s_flat[b][n*64+d] = detal * sum_c inp[b,c,n]*Tc[c,d] ----------------
__global__ __launch_bounds__(256) void k_co(
    const float* __restrict__ inp, const float* __restrict__ Tc,
    const float* __restrict__ detal, float* __restrict__ s)
{
    __shared__ float tc[64 * 68];    // [c][d], stride 68
    __shared__ float xs[64 * 132];   // [c][n], stride 132
    const int b  = blockIdx.y;
    const int n0 = blockIdx.x * 128;
    const int t  = threadIdx.x;
    const int d4 = (t & 15) * 4;
    const int g8 = (t >> 4) * 8;

    {
        const int sr = t >> 2, sc = (t & 3) * 4;
        const float* src = inp + ((size_t)b * CC + sr) * NN + n0;
        float* dst = xs + sr * 132;
#pragma unroll
        for (int k = 0; k < 8; k++)
            *(float4*)(dst + sc + 16 * k) = *(const float4*)(src + sc + 16 * k);
        const float* tsrc = Tc + (size_t)b * 4096 + sr * 64;
        float* tdst = tc + sr * 68;
#pragma unroll
        for (int k = 0; k < 4; k++)
            *(float4*)(tdst + sc + 16 * k) = *(const float4*)(tsrc + sc + 16 * k);
    }
    __syncthreads();

    float acc[8][4];
#pragma unroll
    for (int i = 0; i < 8; i++)
#pragma unroll
        for (int j = 0; j < 4; j++) acc[i][j] = 0.f;

#pragma unroll 4
    for (int c = 0; c < 64; c++) {
        const float4 t4 = *(const float4*)(tc + c * 68 + d4);
        const float4 xa = *(const float4*)(xs + c * 132 + g8);
        const float4 xb = *(const float4*)(xs + c * 132 + g8 + 4);
        const float xv[8] = {xa.x, xa.y, xa.z, xa.w, xb.x, xb.y, xb.z, xb.w};
        const float tv[4] = {t4.x, t4.y, t4.z, t4.w};
#pragma unroll
        for (int i = 0; i < 8; i++)
#pragma unroll
            for (int j = 0; j < 4; j++) acc[i][j] += xv[i] * tv[j];
    }
    const float scl = detal[0];
    float* sb = s + (size_t)b * CC * NN + (size_t)n0 * 64;
#pragma unroll
    for (int i = 0; i < 8; i++) {
        float4 v = make_float4(acc[i][0] * scl, acc[i][1] * scl,
                               acc[i][2] * scl, acc[i][3] * scl);
        *(float4*)(sb + (size_t)(g8 + i) * 64 + d4) = v;
    }
}

// ---------------- Wo (==Ho): s[b,c,h,v] += 2*detal * sum_w inp[b,c,h,w]*Tw[w,v] ----------------
// grid (CC, 2, NB) = 1024 blocks, block 128 (2 waves). Tile 64h x 128v, 8x8/thread,
// K=128 in 4 chunks of 32 (round-6 version — part of the 446us best config).
__global__ __launch_bounds__(128) void k_wo(
    const float* __restrict__ inp, const float* __restrict__ Tw,
    const float* __restrict__ detal, float* __restrict__ s)
{
    __shared__ float xt[32 * 68];     // [w][h_local 64], stride 68
    __shared__ float twl[32 * 132];   // [w][v], stride 132
    const int b = blockIdx.z, hc = blockIdx.y, c = blockIdx.x;
    const int t = threadIdx.x;
    const int rg = t >> 4;            // 0..7 : h = rg*8..+8
    const int vg = t & 15;            // v cols: vg*4 and 64+vg*4
    const int h0 = hc * 64;

    const float* ip = inp + ((size_t)b * CC + c) * NN + (size_t)h0 * WW;
    const float* twg = Tw + (size_t)b * 16384;

    float acc[8][8];
#pragma unroll
    for (int p = 0; p < 8; p++)
#pragma unroll
        for (int q = 0; q < 8; q++) acc[p][q] = 0.f;

    for (int w0 = 0; w0 < 128; w0 += 32) {
        __syncthreads();
        {   // stage X^T: 64 h-rows, w-chunk 32; thread: h=t>>1, 16 w's
            const int h = t >> 1, wq = (t & 1) * 16;
            const float* src = ip + (size_t)h * WW + w0 + wq;
            float v[16];
            *(float4*)(v)      = *(const float4*)(src);
            *(float4*)(v + 4)  = *(const float4*)(src + 4);
            *(float4*)(v + 8)  = *(const float4*)(src + 8);
            *(float4*)(v + 12) = *(const float4*)(src + 12);
#pragma unroll
            for (int j = 0; j < 16; j++) xt[(wq + j) * 68 + h] = v[j];
        }
        {   // stage Tw rows: [w][v]; thread: w=t>>2, 32 v's
            const int w = t >> 2, cq = (t & 3) * 32;
            const float* src = twg + (size_t)(w0 + w) * 128 + cq;
            float* dst = twl + w * 132 + cq;
#pragma unroll
            for (int k = 0; k < 8; k++)
                *(float4*)(dst + 4 * k) = *(const float4*)(src + 4 * k);
        }
        __syncthreads();
#pragma unroll 4
        for (int w = 0; w < 32; ++w) {
            const float4 ra = *(const float4*)(xt + w * 68 + rg * 8);
            const float4 rb = *(const float4*)(xt + w * 68 + rg * 8 + 4);
            const float4 ta = *(const float4*)(twl + w * 132 + vg * 4);
            const float4 tb = *(const float4*)(twl + w * 132 + 64 + vg * 4);
            const float rv[8] = {ra.x, ra.y, ra.z, ra.w, rb.x, rb.y, rb.z, rb.w};
            const float tv[8] = {ta.x, ta.y, ta.z, ta.w, tb.x, tb.y, tb.z, tb.w};
#pragma unroll
            for (int p = 0; p < 8; p++)
#pragma unroll
                for (int q = 0; q < 8; q++) acc[p][q] += rv[p] * tv[q];
        }
    }

    const float sc2 = 2.0f * detal[0];
    float* sp = s + ((size_t)b * CC + c) * NN + (size_t)h0 * WW;
#pragma unroll
    for (int p = 0; p < 8; ++p) {
        const int h = rg * 8 + p;
        float* q0 = sp + (size_t)h * WW + vg * 4;
        float* q1 = sp + (size_t)h * WW + 64 + vg * 4;
        float4 c0 = *(const float4*)q0;
        float4 c1 = *(const float4*)q1;
        c0.x += sc2 * acc[p][0]; c0.y += sc2 * acc[p][1];
        c0.z += sc2 * acc[p][2]; c0.w += sc2 * acc[p][3];
        c1.x += sc2 * acc[p][4]; c1.y += sc2 * acc[p][5];
        c1.z += sc2 * acc[p][6]; c1.w += sc2 * acc[p][7];
        *(float4*)q0 = c0;
        *(float4*)q1 = c1;
    }
}

// ---------------- outconv: out[b,o,n] = sum_c w_out[o,c]*s[b,c,n] + b_out[o] + x[b,o,n] ----------------
// NEW TILE: 256o x 64n, grid (NN/64, NB) = 2048 blocks, block 256, 8x8/thread, K=64 in
// chunks of 16. Reads s exactly ONCE (was 4x with o-chunked grid: -100 MB HBM); wot
// re-reads served by L2 (64 KB resident). 21 KB LDS + 2048 blocks -> ~7 blocks/CU, so
// staging latency overlaps across blocks (vs 2/CU before). HBM floor: 33.5(s)+134(x)
// +134(out) = 302 MB = 48 us.
__global__ __launch_bounds__(256) void k_outconv(
    const float* __restrict__ s, const float* __restrict__ wot,
    const float* __restrict__ b_out, const float* __restrict__ x,
    float* __restrict__ outp)
{
    __shared__ float ss[16 * 68];    // [c][n 64], stride 68, 4.3 KB
    __shared__ float wl[16 * 260];   // [c][o 256], stride 260, 16.6 KB
    const int b  = blockIdx.y;
    const int n0 = blockIdx.x * 64;
    const int t  = threadIdx.x;
    const int og = t >> 3;           // 0..31 : o = og*8..+8
    const int ng = t & 7;            // n quads: n0+ng*4 and n0+32+ng*4

    const int sr = t >> 4;           // staging row 0..15
    const int sq = (t & 15) * 4;     // s cols (4 floats)
    const int wq = (t & 15) * 16;    // w cols (16 floats)
    const float* sbase = s + ((size_t)b * CC + sr) * NN + n0 + sq;
    const float* wbase = wot + (size_t)sr * IC + wq;
    float* sdst = ss + sr * 68 + sq;
    float* wdst = wl + sr * 260 + wq;

    float acc[8][8];
#pragma unroll
    for (int p = 0; p < 8; p++)
#pragma unroll
        for (int q = 0; q < 8; q++) acc[p][q] = 0.f;

    for (int c0 = 0; c0 < CC; c0 += 16) {
        __syncthreads();
        {
            const float4 a0 = *(const float4*)(sbase + (size_t)c0 * NN);
            const float* wsrc = wbase + (size_t)c0 * IC;
            const float4 w0 = *(const float4*)(wsrc);
            const float4 w1 = *(const float4*)(wsrc + 4);
            const float4 w2 = *(const float4*)(wsrc + 8);
            const float4 w3 = *(const float4*)(wsrc + 12);
            *(float4*)(sdst)      = a0;
            *(float4*)(wdst)      = w0;
            *(float4*)(wdst + 4)  = w1;
            *(float4*)(wdst + 8)  = w2;
            *(float4*)(wdst + 12) = w3;
        }
        __syncthreads();
#pragma unroll 4
        for (int c = 0; c < 16; ++c) {
            const float4 wa = *(const float4*)(wl + c * 260 + og * 8);
            const float4 wb = *(const float4*)(wl + c * 260 + og * 8 + 4);
            const float4 sa = *(const float4*)(ss + c * 68 + ng * 4);
            const float4 sb = *(const float4*)(ss + c * 68 + 32 + ng * 4);
            const float wv[8] = {wa.x, wa.y, wa.z, wa.w, wb.x, wb.y, wb.z, wb.w};
            const float sv[8] = {sa.x, sa.y, sa.z, sa.w, sb.x, sb.y, sb.z, sb.w};
#pragma unroll
            for (int p = 0; p < 8; p++)
#pragma unroll
                for (int q = 0; q < 8; q++) acc[p][q] += wv[p] * sv[q];
        }
    }

#pragma unroll
    for (int p = 0; p < 8; ++p) {
        const int oo = og * 8 + p;
        const float bo = b_out[oo];
        const float* xb = x + ((size_t)b * IC + oo) * NN + n0;
        float* ob = outp + ((size_t)b * IC + oo) * NN + n0;
        const float4 x0 = *(const float4*)(xb + ng * 4);
        const float4 x1 = *(const float4*)(xb + 32 + ng * 4);
        *(float4*)(ob + ng * 4) =
            make_float4(acc[p][0] + bo + x0.x, acc[p][1] + bo + x0.y,
                        acc[p][2] + bo + x0.z, acc[p][3] + bo + x0.w);
        *(float4*)(ob + 32 + ng * 4) =
            make_float4(acc[p][4] + bo + x1.x, acc[p][5] + bo + x1.y,
                        acc[p][6] + bo + x1.z, acc[p][7] + bo + x1.w);
    }
}

extern "C" void kernel_launch(void* const* d_in, const int* in_sizes, int n_in,
                              void* d_out, int out_size, void* d_ws, size_t ws_size,
                              hipStream_t stream)
{
    const float* x     = (const float*)d_in[0];
    const float* w_in  = (const float*)d_in[1];
    const float* b_in  = (const float*)d_in[2];
    const float* w_out = (const float*)d_in[3];
    const float* b_out = (const float*)d_in[4];
    const float* detal = (const float*)d_in[5];
    float* out = (float*)d_out;

    float* ws   = (float*)d_ws;
    float* inp  = ws + OFF_INP;
    float* s    = ws + OFF_S;
    float* pW   = ws + OFF_S;      // aliased with s (pW dead before k_co writes s)
    float* pC   = ws + OFF_PC;
    float* Tw   = ws + OFF_TW;
    float* Tc   = ws + OFF_TC;
    float* wt   = ws + OFF_WT;
    float* wot  = ws + OFF_WOT;

    k_wt     <<<dim3(128),              256, 0, stream>>>(w_in, w_out, wt, wot);
    k_inconv <<<dim3(NN / 256, NB),     256, 0, stream>>>(x, wt, b_in, inp);
    k_gramW  <<<dim3(NKW, NB),          256, 0, stream>>>(inp, pW);
    k_redW   <<<dim3(64, NB),           256, 0, stream>>>(pW, Tw);
    k_softW  <<<dim3(NB, 4),           1024, 0, stream>>>(Tw);
    k_gramC  <<<dim3(NKC, NB),          256, 0, stream>>>(inp, pC);
    k_redC   <<<dim3(16, NB),           256, 0, stream>>>(pC, Tc);
    k_softC  <<<dim3(NB),              1024, 0, stream>>>(Tc);
    k_co     <<<dim3(NN / 128, NB),     256, 0, stream>>>(inp, Tc, detal, s);
    k_wo     <<<dim3(CC, 2, NB),        128, 0, stream>>>(inp, Tw, detal, s);
    k_outconv<<<dim3(NN / 64, NB),      256, 0, stream>>>(s, wot, b_out, x, out);
}